// Round 11
// baseline (458.366 us; speedup 1.0000x reference)
//
#include <hip/hip_runtime.h>
#include <hip/hip_bf16.h>

// C[M,N] = A[M,K] @ W[N,K]^T ; M=32768, N=K=2048. fp32 in/out.
// R11: cut LDS traffic — A staged via gload_lds (swizzled, as R7), W (B-operand)
// read DIRECTLY from global/L2 into fragments (W is 8.4MB bf16, L2/L3-hot).
// Per-wave per K-tile: 16 ds_read_b128 (A only) + 4 gload_lds + 8 global B
// loads + 64 MFMA. LDS/CU/K-tile 1536 cyc < MFMA floor 2480 cyc (was 2300).
// vmcnt ledger (issue order: stages(t+1) x4, then B(t+1) x8):
//   tile entry: outstanding = 8 B(t).  +4 stages -> 12.
//   gate vmcnt(4) before MFMAs: drains B(t) (oldest 8), leaves stages(t+1).
//   after MFMAs: issue B(t+1) -> 12. boundary gate vmcnt(8): drains stages,
//   keeps B(t+1) in flight across the barrier. Peel tile: vmcnt(0).

typedef __attribute__((ext_vector_type(8))) short bf16x8;
typedef __attribute__((ext_vector_type(4))) float f32x4;

#define M_DIM 32768
#define N_DIM 2048
#define K_DIM 2048
#define BM 256
#define BN 256
#define BK 64
#define NT (K_DIM / BK)              // 32
#define NBN (N_DIM / BN)             // 8
#define NWG ((M_DIM / BM) * NBN)     // 1024

typedef __attribute__((address_space(3))) char lds_char;
typedef __attribute__((address_space(1))) char glb_char;

__device__ __forceinline__ unsigned short f2bf(float f) {
    __bf16 b = (__bf16)f;   // RNE
    return __builtin_bit_cast(unsigned short, b);
}

// ---------------- fp32 -> bf16 convert (memory-bound, grid-stride) ----------
__global__ __launch_bounds__(256)
void cvt_f32_bf16(const float* __restrict__ src, ushort* __restrict__ dst, int n8) {
    const float4* s4 = (const float4*)src;
    int idx = blockIdx.x * blockDim.x + threadIdx.x;
    int stride = gridDim.x * blockDim.x;
    for (int i = idx; i < n8; i += stride) {
        float4 a = s4[2 * (size_t)i];
        float4 b = s4[2 * (size_t)i + 1];
        ushort r[8] = {f2bf(a.x), f2bf(a.y), f2bf(a.z), f2bf(a.w),
                       f2bf(b.x), f2bf(b.y), f2bf(b.z), f2bf(b.w)};
        *reinterpret_cast<uint4*>(dst + 8 * (size_t)i) =
            *reinterpret_cast<const uint4*>(r);
    }
}

// ---------------- 256^2 8-wave, A-in-LDS / B-direct bf16 GEMM ---------------
__global__ __launch_bounds__(512, 2)
void agmm_bdir(const ushort* __restrict__ A, const ushort* __restrict__ W,
               float* __restrict__ C) {
    // sA only: buf*32768 (256 rows x 64 cols bf16, 128B rows). 64 KiB total.
    __shared__ __attribute__((aligned(16))) char sm[65536];

    const int tid  = threadIdx.x;
    const int lane = tid & 63;
    const int w    = tid >> 6;      // 0..7
    const int wm   = w >> 2;        // 0..1 -> 128-row half of A tile
    const int wn   = w & 3;         // 0..3 -> 64-col slice of B tile

    const int bid = blockIdx.x;
    const int swz = (bid & 7) * (NWG / 8) + (bid >> 3);  // bijective (NWG%8==0)
    const int bm  = swz >> 3;            // 0..127
    const int bn  = swz & (NBN - 1);     // 0..7

    // A staging source pre-swizzle (linear LDS dest; read applies same XOR)
    const int lsub = lane >> 3;                       // row&7 at dest
    const int scol = ((lane & 7) ^ lsub) << 3;        // pre-swizzled col elems

    const ushort* Abase = A + (size_t)bm * BM * K_DIM + scol;

    const int lrow = lane & 15;
    const int fxor = (lrow & 7) << 4;
    const int kcb0 = (lane >> 4) << 4;    // 0,16,32,48 byte k-offset
    const int offk0 = (0 + kcb0) ^ fxor;
    const int offk1 = (64 + kcb0) ^ fxor;

    const int abC = (wm * 128 + lrow) * 128;           // A row base (buf0)

    // B direct-load base: lane reads 16B at W[bn*256 + wn*64 + n*16 + lrow]
    //                     [kt*64 + kk*32 + (lane>>4)*8]
    const ushort* Wg = W + (size_t)(bn * BN + wn * 64 + lrow) * K_DIM
                         + ((lane >> 4) << 3);

    f32x4 acc[8][4];
#pragma unroll
    for (int m = 0; m < 8; ++m)
#pragma unroll
        for (int n = 0; n < 4; ++n)
            acc[m][n] = (f32x4){0.f, 0.f, 0.f, 0.f};
    bf16x8 afA[2][2], afB[2][2];   // double-banked A frags
    bf16x8 bfr[4][2];              // B frags (global-loaded, live 1 K-tile)

#define GLD16(SRC, LOFF)                                                       \
    __builtin_amdgcn_global_load_lds((const glb_char*)(SRC),                   \
                                     (lds_char*)(sm + (LOFF)), 16, 0, 0)
    // stage FULL A tile (256 rows): 4 loads/wave; wave w covers rows 16w..16w+15
#define STAGE_A2(KT, BUF) do {                                                 \
        const int ra_ = (w << 4);                                              \
        GLD16(Abase + (size_t)(ra_ + lsub) * K_DIM + (KT) * BK,                \
              (BUF) * 32768 + ra_ * 128);                                      \
        GLD16(Abase + (size_t)(ra_ + 8 + lsub) * K_DIM + (KT) * BK,            \
              (BUF) * 32768 + (ra_ + 8) * 128);                                \
        GLD16(Abase + (size_t)(128 + ra_ + lsub) * K_DIM + (KT) * BK,          \
              (BUF) * 32768 + (128 + ra_) * 128);                              \
        GLD16(Abase + (size_t)(128 + ra_ + 8 + lsub) * K_DIM + (KT) * BK,      \
              (BUF) * 32768 + (128 + ra_ + 8) * 128);                          \
    } while (0)

    // direct B fragment load for K-tile KT (8 x global_load_dwordx4)
#define LD_B(KT) do {                                                          \
        _Pragma("unroll") for (int n = 0; n < 4; ++n) {                        \
            bfr[n][0] = *(const bf16x8*)(Wg + (size_t)n * 16 * K_DIM +         \
                                         (KT) * BK);                           \
            bfr[n][1] = *(const bf16x8*)(Wg + (size_t)n * 16 * K_DIM +         \
                                         (KT) * BK + 32);                      \
        }                                                                      \
    } while (0)

#define RD_A(MT, ABASE, DST) do {                                              \
        _Pragma("unroll") for (int m2 = 0; m2 < 2; ++m2) {                     \
            DST[m2][0] = *(const bf16x8*)(sm + (ABASE) +                       \
                ((MT) * 32 + m2 * 16) * 128 + offk0);                          \
            DST[m2][1] = *(const bf16x8*)(sm + (ABASE) +                       \
                ((MT) * 32 + m2 * 16) * 128 + offk1);                          \
        }                                                                      \
    } while (0)
#define MFMA_Q(Q, AF) do {                                                     \
        __builtin_amdgcn_s_setprio(1);                                         \
        _Pragma("unroll") for (int m2 = 0; m2 < 2; ++m2)                       \
        _Pragma("unroll") for (int n = 0; n < 4; ++n)                          \
        _Pragma("unroll") for (int kk = 0; kk < 2; ++kk)                       \
            acc[(Q) * 2 + m2][n] = __builtin_amdgcn_mfma_f32_16x16x32_bf16(    \
                AF[m2][kk], bfr[n][kk], acc[(Q) * 2 + m2][n], 0, 0, 0);        \
        __builtin_amdgcn_s_setprio(0);                                         \
    } while (0)

#define VMW(N)  asm volatile("s_waitcnt vmcnt(" #N ")" ::: "memory")
#define BOUNDARY do {                                                          \
        __builtin_amdgcn_s_barrier();                                          \
        __builtin_amdgcn_sched_barrier(0);                                     \
    } while (0)

    // prologue: stage A(0) (4 loads), issue B(0) (8 loads);
    // vmcnt(8) drains the 4 stages (oldest), keeps B(0) in flight.
    STAGE_A2(0, 0);
    LD_B(0);
    VMW(8);
    BOUNDARY;

    for (int t = 0; t < NT - 1; ++t) {
        const int cur   = t & 1;
        const int nxt   = cur ^ 1;
        const int abase = cur * 32768 + abC;
        RD_A(0, abase, afA);
        RD_A(1, abase, afB);
        STAGE_A2(t + 1, nxt);      // +4 -> 12 outstanding
        VMW(4);                    // drain B(t) (oldest 8); stages remain
        MFMA_Q(0, afA);
        RD_A(2, abase, afA);
        MFMA_Q(1, afB);
        RD_A(3, abase, afB);
        MFMA_Q(2, afA);
        MFMA_Q(3, afB);
        LD_B(t + 1);               // +8 -> 12 outstanding
        VMW(8);                    // drain stages(t+1); keep B(t+1) in flight
        BOUNDARY;
    }
    {   // last tile (parity 1): no staging, drain B fully
        const int abase = 32768 + abC;
        RD_A(0, abase, afA);
        RD_A(1, abase, afB);
        VMW(0);                    // B(NT-1) landed
        MFMA_Q(0, afA);
        RD_A(2, abase, afA);
        MFMA_Q(1, afB);
        RD_A(3, abase, afB);
        MFMA_Q(2, afA);
        MFMA_Q(3, afB);
    }
#undef BOUNDARY
#undef VMW
#undef MFMA_Q
#undef RD_A
#undef LD_B
#undef STAGE_A2
#undef GLD16

    // epilogue: C/D layout col=lane&15, row=(lane>>4)*4+reg (R1-R10 validated)
    const size_t crow = (size_t)(bm * BM + wm * 128 + ((lane >> 4) << 2));
    const int    ccol = bn * BN + wn * 64 + (lane & 15);
    float* Cp = C + crow * N_DIM + ccol;
#pragma unroll
    for (int m = 0; m < 8; ++m)
#pragma unroll
        for (int j = 0; j < 4; ++j) {
            float* cr = Cp + (size_t)(m * 16 + j) * N_DIM;
#pragma unroll
            for (int n = 0; n < 4; ++n)
                cr[n * 16] = acc[m][n][j];
        }
}

// ---------------- fused fp32 fallback (ws too small; R1-validated) ----------
__global__ __launch_bounds__(256, 2)
void agmm_fused(const float* __restrict__ A, const float* __restrict__ W,
                float* __restrict__ C) {
    __shared__ __attribute__((aligned(16))) char sA[128 * 64 * 2];
    __shared__ __attribute__((aligned(16))) char sB[128 * 64 * 2];

    const int tid  = threadIdx.x;
    const int lane = tid & 63;
    const int wid  = tid >> 6;
    const int wm   = wid >> 1;
    const int wn   = wid & 1;

    const int nwg = (M_DIM / 128) * (N_DIM / 128);
    const int bid = blockIdx.x;
    const int swz = (bid & 7) * (nwg / 8) + (bid >> 3);
    const int bm  = swz >> 4;
    const int bn  = swz & 15;

    const int srow = tid >> 4;
    const int scol = (tid & 15) << 2;

    const float* Ap = A + (size_t)(bm * 128 + srow) * K_DIM + scol;
    const float* Wp = W + (size_t)(bn * 128 + srow) * K_DIM + scol;
    const int wbase = (srow * 128 + (scol << 1)) ^ ((srow & 7) << 4);

    const int lrow = lane & 15;
    const int lkb  = (lane >> 4) << 3;
    const int fxor = (lrow & 7) << 4;
    const int arow0 = (wm * 64 + lrow) * 128;
    const int brow0 = (wn * 64 + lrow) * 128;

    f32x4 acc[4][4];
#pragma unroll
    for (int m = 0; m < 4; ++m)
#pragma unroll
        for (int n = 0; n < 4; ++n)
            acc[m][n] = (f32x4){0.f, 0.f, 0.f, 0.f};

    float4 areg[8], breg[8];
#pragma unroll
    for (int p = 0; p < 8; ++p) {
        areg[p] = *reinterpret_cast<const float4*>(Ap + (size_t)p * 16 * K_DIM);
        breg[p] = *reinterpret_cast<const float4*>(Wp + (size_t)p * 16 * K_DIM);
    }

    for (int kt = 0; kt < NT; ++kt) {
        __syncthreads();
#pragma unroll
        for (int p = 0; p < 8; ++p) {
            ushort av[4] = {f2bf(areg[p].x), f2bf(areg[p].y),
                            f2bf(areg[p].z), f2bf(areg[p].w)};
            *reinterpret_cast<ushort4*>(sA + (wbase + p * 2048)) =
                *reinterpret_cast<ushort4*>(av);
            ushort bv[4] = {f2bf(breg[p].x), f2bf(breg[p].y),
                            f2bf(breg[p].z), f2bf(breg[p].w)};
            *reinterpret_cast<ushort4*>(sB + (wbase + p * 2048)) =
                *reinterpret_cast<ushort4*>(bv);
        }
        __syncthreads();

        if (kt + 1 < NT) {
            const float* ap = Ap + (size_t)(kt + 1) * BK;
            const float* wp = Wp + (size_t)(kt + 1) * BK;
#pragma unroll
            for (int p = 0; p < 8; ++p) {
                areg[p] = *reinterpret_cast<const float4*>(ap + (size_t)p * 16 * K_DIM);
                breg[p] = *reinterpret_cast<const float4*>(wp + (size_t)p * 16 * K_DIM);
            }
        }

#pragma unroll
        for (int kk = 0; kk < 2; ++kk) {
            const int kcb = (kk * 32 + lkb) * 2;
            bf16x8 af[4], bfv[4];
#pragma unroll
            for (int m = 0; m < 4; ++m)
                af[m] = *reinterpret_cast<const bf16x8*>(
                    sA + ((arow0 + m * 2048 + kcb) ^ fxor));
#pragma unroll
            for (int n = 0; n < 4; ++n)
                bfv[n] = *reinterpret_cast<const bf16x8*>(
                    sB + ((brow0 + n * 2048 + kcb) ^ fxor));
#pragma unroll
            for (int m = 0; m < 4; ++m)
#pragma unroll
                for (int n = 0; n < 4; ++n)
                    acc[m][n] = __builtin_amdgcn_mfma_f32_16x16x32_bf16(
                        af[m], bfv[n], acc[m][n], 0, 0, 0);
        }
    }

    const size_t crow = (size_t)(bm * 128 + wm * 64 + ((lane >> 4) << 2));
    const int    ccol = bn * 128 + wn * 64 + (lane & 15);
    float* Cp = C + crow * N_DIM + ccol;
#pragma unroll
    for (int m = 0; m < 4; ++m)
#pragma unroll
        for (int j = 0; j < 4; ++j) {
            float* cr = Cp + (size_t)(m * 16 + j) * N_DIM;
#pragma unroll
            for (int n = 0; n < 4; ++n)
                cr[n * 16] = acc[m][n][j];
        }
}

extern "C" void kernel_launch(void* const* d_in, const int* in_sizes, int n_in,
                              void* d_out, int out_size, void* d_ws, size_t ws_size,
                              hipStream_t stream) {
    const float* A  = (const float*)d_in[0];   // [8,4096,2048] fp32
    const float* Wt = (const float*)d_in[1];   // [2048,2048] fp32
    float* C = (float*)d_out;                  // [32768,2048] fp32

    const size_t needA = (size_t)M_DIM * K_DIM * 2;
    const size_t needW = (size_t)N_DIM * K_DIM * 2;

    if (ws_size >= needA + needW) {
        ushort* Abf = (ushort*)d_ws;
        ushort* Wbf = (ushort*)((char*)d_ws + needA);
        cvt_f32_bf16<<<dim3(2048), dim3(256), 0, stream>>>(A, Abf, (M_DIM * K_DIM) / 8);
        cvt_f32_bf16<<<dim3(2048), dim3(256), 0, stream>>>(Wt, Wbf, (N_DIM * K_DIM) / 8);
        agmm_bdir<<<dim3(NWG), dim3(512), 0, stream>>>(Abf, Wbf, C);
    } else {
        agmm_fused<<<dim3((M_DIM / 128) * (N_DIM / 128)), dim3(256), 0, stream>>>(A, Wt, C);
    }
}